// Round 1
// baseline (422.062 us; speedup 1.0000x reference)
//
#include <hip/hip_runtime.h>

// Fused causal attention head: B=4, T=4096, D=384, K=64.
// All operands FRAGMENT-LINEAR for 32x32x16 MFMA: frag = [lane(64)][j(8)] u16 (1KB),
// index: lane&31 = m/n, lane>>5 = k-half, j = k&7; ksegs of 16 k each.
// Yk/Yq: tile(b, t32) = 4 ksegs (feat 0..63)            -> 2048 u16
// Vt:    tile(b, d>>5, key>>7) = 8 ksegs (128 keys)     -> 4096 u16
// Wka/Wqa: tile(fout>>5) x 24 ksegs (fin)               -> 12288 u16 each x2
// Wvb:     tile(d>>5)    x 24 ksegs (fin)               -> 12288 u16 x12
// Softmax: fixed-base (no max) — scores/8 ~ O(1), exp2 args small, fp32-safe.

#define BB 4
#define TT 4096
#define DD 384

#define OWKA 0
#define OWQA 24576
#define OWVB 49152
#define OYK  196608
#define OYQ  1245184
#define OVT  2293760

#define C_EXP 0.18033688011112042f  // log2(e)/8

typedef __bf16 bf16x8 __attribute__((ext_vector_type(8)));
typedef float f32x16 __attribute__((ext_vector_type(16)));
typedef unsigned short u16x4 __attribute__((ext_vector_type(4)));

__device__ __forceinline__ unsigned short f2bf(float f) {
  unsigned int u = __builtin_bit_cast(unsigned int, f);
  u += 0x7FFFu + ((u >> 16) & 1u);
  return (unsigned short)(u >> 16);
}

__device__ __forceinline__ bf16x8 ldb8(const unsigned short* p) {
  return *reinterpret_cast<const bf16x8*>(p);
}

// ---------------- 1. Weight convert -> frag-linear (Wk/Wq A-frag, Wv B-frag) --------
__global__ __launch_bounds__(256) void convert_w(
    const float* __restrict__ Wk, const float* __restrict__ Wq,
    const float* __restrict__ Wv, unsigned short* __restrict__ ws) {
  int g = blockIdx.x * 256 + threadIdx.x;    // 512 rows x 96 float4 = 49152
  int row = g / 96;
  int fin = (g - row * 96) * 4;
  const float* src;
  unsigned short* dstbase;
  int m;
  if (row < 64)       { src = Wk + row * 384;         dstbase = ws + OWKA; m = row; }
  else if (row < 128) { src = Wq + (row - 64) * 384;  dstbase = ws + OWQA; m = row - 64; }
  else                { src = Wv + (row - 128) * 384; dstbase = ws + OWVB; m = row - 128; }
  float4 f = *reinterpret_cast<const float4*>(src + fin);
  u16x4 o;
  o[0] = f2bf(f.x); o[1] = f2bf(f.y); o[2] = f2bf(f.z); o[3] = f2bf(f.w);
  unsigned short* dst = dstbase + (m >> 5) * 12288 + (fin >> 4) * 512
                        + ((((fin >> 3) & 1) << 5) + (m & 31)) * 8 + (fin & 7);
  *reinterpret_cast<u16x4*>(dst) = o;
}

// ---------------- 2. Fused K/Q/V projection ----------------------------------------
// Block = 64 tokens, 512 threads (8 waves). X staged once in LDS frag-linear
// (serves as B-frag for K/Q and A-frag for V). Waves 0-1: Yk/Yq; waves 2-7: V.
__global__ __launch_bounds__(512) void proj_fused(
    const float* __restrict__ x, const unsigned short* __restrict__ ws_r,
    unsigned short* __restrict__ Yk, unsigned short* __restrict__ Yq,
    unsigned short* __restrict__ Vt) {
  __shared__ __align__(16) unsigned short xlds[24576];   // [t32(2)][kseg(24)][64][8]
  int tb = blockIdx.x;                        // 0..255
  int b = tb >> 6;
  int tid = threadIdx.x;
  // stage X: row r = tid>>3 (64 rows), e = tid&7 (segment of 48 feats)
  {
    int r = tid >> 3, e = tid & 7;
    const float* xr = x + (tb * 64 + r) * DD + e * 48;
#pragma unroll
    for (int i = 0; i < 12; i++) {
      int fin = e * 48 + i * 4;
      float4 f = *reinterpret_cast<const float4*>(xr + i * 4);
      u16x4 o;
      o[0] = f2bf(f.x); o[1] = f2bf(f.y); o[2] = f2bf(f.z); o[3] = f2bf(f.w);
      unsigned short* dst = xlds + (r >> 5) * 12288 + (fin >> 4) * 512
                            + ((((fin >> 3) & 1) << 5) + (r & 31)) * 8 + (fin & 7);
      *reinterpret_cast<u16x4*>(dst) = o;
    }
  }
  __syncthreads();
  int wid = tid >> 6, lane = tid & 63;
  int l31 = lane & 31, h8 = lane >> 5;
  const f32x16 fz16 = {};
  if (wid < 2) {
    // Yk (wid 0) / Yq (wid 1): A = W[2 mtiles], B = X[2 ntiles]
    const unsigned short* Wa = ws_r + (wid ? OWQA : OWKA) + lane * 8;
    unsigned short* Ysel = (wid ? Yq : Yk);
    f32x16 acc[2][2];
    acc[0][0] = fz16; acc[0][1] = fz16; acc[1][0] = fz16; acc[1][1] = fz16;
    for (int ks = 0; ks < 24; ks++) {
      bf16x8 a0 = ldb8(Wa + ks * 512);
      bf16x8 a1 = ldb8(Wa + 12288 + ks * 512);
      bf16x8 b0 = ldb8(xlds + ks * 512 + lane * 8);
      bf16x8 b1 = ldb8(xlds + 12288 + ks * 512 + lane * 8);
      acc[0][0] = __builtin_amdgcn_mfma_f32_32x32x16_bf16(a0, b0, acc[0][0], 0, 0, 0);
      acc[0][1] = __builtin_amdgcn_mfma_f32_32x32x16_bf16(a0, b1, acc[0][1], 0, 0, 0);
      acc[1][0] = __builtin_amdgcn_mfma_f32_32x32x16_bf16(a1, b0, acc[1][0], 0, 0, 0);
      acc[1][1] = __builtin_amdgcn_mfma_f32_32x32x16_bf16(a1, b1, acc[1][1], 0, 0, 0);
    }
    // C[fout = mt*32 + rg*8+4h8+i][token = tb*64 + nt*32 + l31]
#pragma unroll
    for (int mt = 0; mt < 2; mt++)
#pragma unroll
      for (int nt = 0; nt < 2; nt++) {
        int tile = b * 128 + (tb & 63) * 2 + nt;
#pragma unroll
        for (int rg = 0; rg < 4; rg++) {
          u16x4 o;
#pragma unroll
          for (int i = 0; i < 4; i++) o[i] = f2bf(acc[mt][nt][rg * 4 + i]);
          *reinterpret_cast<u16x4*>(Ysel + tile * 2048 + (mt * 2 + (rg >> 1)) * 512
                                    + (((rg & 1) << 5) + l31) * 8 + 4 * h8) = o;
        }
      }
  } else {
    // V: A = X[2 token tiles], B = Wv[2 d-tiles]; vw in [0,6)
    int vw = wid - 2;
    const unsigned short* Wb = ws_r + OWVB + vw * 2 * 12288 + lane * 8;
    f32x16 acc[2][2];
    acc[0][0] = fz16; acc[0][1] = fz16; acc[1][0] = fz16; acc[1][1] = fz16;
    for (int ks = 0; ks < 24; ks++) {
      bf16x8 a0 = ldb8(xlds + ks * 512 + lane * 8);
      bf16x8 a1 = ldb8(xlds + 12288 + ks * 512 + lane * 8);
      bf16x8 w0 = ldb8(Wb + ks * 512);
      bf16x8 w1 = ldb8(Wb + 12288 + ks * 512);
      acc[0][0] = __builtin_amdgcn_mfma_f32_32x32x16_bf16(a0, w0, acc[0][0], 0, 0, 0);
      acc[0][1] = __builtin_amdgcn_mfma_f32_32x32x16_bf16(a0, w1, acc[0][1], 0, 0, 0);
      acc[1][0] = __builtin_amdgcn_mfma_f32_32x32x16_bf16(a1, w0, acc[1][0], 0, 0, 0);
      acc[1][1] = __builtin_amdgcn_mfma_f32_32x32x16_bf16(a1, w1, acc[1][1], 0, 0, 0);
    }
    // C[key = tb*64 + t32*32 + rg*8+4h8+i][d = vw*64 + dt*32 + l31]
    int k128 = (tb & 63) >> 1;               // key-block WITHIN batch
#pragma unroll
    for (int t32 = 0; t32 < 2; t32++)
#pragma unroll
      for (int dt = 0; dt < 2; dt++) {
        int dti = vw * 2 + dt;
        unsigned short* vbase = Vt + ((b * 12 + dti) * 32 + k128) * 4096;
#pragma unroll
        for (int rg = 0; rg < 4; rg++) {
          u16x4 o;
#pragma unroll
          for (int i = 0; i < 4; i++) o[i] = f2bf(acc[t32][dt][rg * 4 + i]);
          int kseg = 4 * (tb & 1) + t32 * 2 + (rg >> 1);
          *reinterpret_cast<u16x4*>(vbase + kseg * 512
                                    + (((rg & 1) << 5) + l31) * 8 + 4 * h8) = o;
        }
      }
  }
}

// ---------------- 3. Flash attention: 8-wave blocks, in-block key split ------------
// b = (blk&7)>>1: each XCD works one batch -> Vt(b)+Yk(b) ~3.6MB fits its 4MB L2.
// Two 4-wave groups per block: group g handles key-blocks kb = 2*it + g.
// Wall iterations halve (1..16), resident waves 16/CU while pairs overlap, 8 floor.
// Odd tail (kb == n128) is masked for free: its keys >= n128*128 > qrow, so the
// causal test zeroes P; only addresses are clamped. LDS = 64KB exactly (2 blocks/CU),
// reused as fp32 staging for the cross-group acc + psum reduction at the end.
__global__ __launch_bounds__(512, 4) void flash_attn(
    const unsigned short* __restrict__ Yk, const unsigned short* __restrict__ Yq,
    const unsigned short* __restrict__ Vt, float* __restrict__ out) {
  __shared__ __align__(16) unsigned short pbuf[2][2][8192];  // [group][dbuf][kseg(8)][lane(64)][j(8)]
  int blk = blockIdx.x;
  int xcd = blk & 7;
  int b = xcd >> 1, half = xcd & 1;
  int n = blk >> 3;
  int st = (n < 32) ? (127 - 2 * n - half) : (2 * (n - 32) + half);
  int tid = threadIdx.x;
  int wid = tid >> 6, lane = tid & 63;
  int g = wid >> 2, wg = wid & 3;
  int l31 = lane & 31, h8 = lane >> 5;
  const f32x16 fz16 = {};
  const unsigned short* qbase = Yq + (b * 128 + st) * 2048 + lane * 8;
  bf16x8 qf[4];
#pragma unroll
  for (int ks = 0; ks < 4; ks++) qf[ks] = ldb8(qbase + ks * 512);
  f32x16 acc[3];
  acc[0] = fz16; acc[1] = fz16; acc[2] = fz16;
  float psum = 0.f;
  int n128 = (st >> 2) + 1;
  int W = (n128 + 1) >> 1;                   // wall iterations (uniform per block)
  int qrow = st * 32 + l31;
  const unsigned short* kbase = Yk + (b * 128 + wg) * 2048 + lane * 8;
  const unsigned short* vbase = Vt + ((b * 12 + wg * 3) * 32) * 4096 + lane * 8;
#pragma unroll 1
  for (int it = 0; it < W; it++) {
    int kb = 2 * it + g;
    int kbc = (kb < n128) ? kb : (n128 - 1);   // clamp addresses; P masked by causal test
    const unsigned short* kt = kbase + kbc * 8192;
    bf16x8 kf[4];
#pragma unroll
    for (int ks = 0; ks < 4; ks++) kf[ks] = ldb8(kt + ks * 512);
    f32x16 sacc = fz16;
#pragma unroll
    for (int ks = 0; ks < 4; ks++)
      sacc = __builtin_amdgcn_mfma_f32_32x32x16_bf16(kf[ks], qf[ks], sacc, 0, 0, 0);
    int kg0 = kb * 128 + wg * 32 + 4 * h8;     // real kb: masked iters have key > qrow
    unsigned short* pw = pbuf[g][it & 1];
#pragma unroll
    for (int rg = 0; rg < 4; rg++) {
      u16x4 o;
#pragma unroll
      for (int i = 0; i < 4; i++) {
        int key = kg0 + rg * 8 + i;
        float pv = (key > qrow) ? 0.f : exp2f(sacc[rg * 4 + i] * C_EXP);
        psum += pv;
        o[i] = f2bf(pv);
      }
      int gq = wg * 2 + (rg >> 1);
      *reinterpret_cast<u16x4*>(pw + gq * 512 + ((rg & 1) * 32 + l31) * 8 + 4 * h8) = o;
    }
    const unsigned short* vt = vbase + kbc * 4096;
    bf16x8 vf0[8], vf1[8], vf2[8];
#pragma unroll
    for (int q = 0; q < 8; q++) vf0[q] = ldb8(vt + q * 512);
#pragma unroll
    for (int q = 0; q < 8; q++) vf1[q] = ldb8(vt + 32 * 4096 + q * 512);
#pragma unroll
    for (int q = 0; q < 8; q++) vf2[q] = ldb8(vt + 64 * 4096 + q * 512);
    __syncthreads();
    bf16x8 pf[8];
#pragma unroll
    for (int q = 0; q < 8; q++) pf[q] = ldb8(pw + q * 512 + lane * 8);
#pragma unroll
    for (int q = 0; q < 8; q++) {
      acc[0] = __builtin_amdgcn_mfma_f32_32x32x16_bf16(vf0[q], pf[q], acc[0], 0, 0, 0);
      acc[1] = __builtin_amdgcn_mfma_f32_32x32x16_bf16(vf1[q], pf[q], acc[1], 0, 0, 0);
      acc[2] = __builtin_amdgcn_mfma_f32_32x32x16_bf16(vf2[q], pf[q], acc[2], 0, 0, 0);
    }
  }
  // ---- cross-group combine: reuse pbuf as fp32 staging ----
  // words [0, 12288): group1 acc (wave wg: wg*3072 + (dt*16+e)*64 + lane)
  // words [12288, 12544): per-wave psum (wid*32 + l31)
  psum += __shfl_xor(psum, 32);
  __syncthreads();                           // all P reads done; safe to overwrite
  float* fb = reinterpret_cast<float*>(pbuf);
  if (h8 == 0) fb[12288 + wid * 32 + l31] = psum;
  if (g == 1) {
#pragma unroll
    for (int dt = 0; dt < 3; dt++)
#pragma unroll
      for (int e = 0; e < 16; e++)
        fb[wg * 3072 + (dt * 16 + e) * 64 + lane] = acc[dt][e];
  }
  __syncthreads();
  if (g == 0) {
    float lt = 0.f;
#pragma unroll
    for (int w = 0; w < 8; w++) lt += fb[12288 + w * 32 + l31];
    float inv = 1.0f / lt;
    float* ob = out + (b * TT + st * 32 + l31) * DD + wg * 96;
#pragma unroll
    for (int dt = 0; dt < 3; dt++)
#pragma unroll
      for (int rg = 0; rg < 4; rg++) {
        float4 o4;
        o4.x = (acc[dt][rg * 4 + 0] + fb[wg * 3072 + (dt * 16 + rg * 4 + 0) * 64 + lane]) * inv;
        o4.y = (acc[dt][rg * 4 + 1] + fb[wg * 3072 + (dt * 16 + rg * 4 + 1) * 64 + lane]) * inv;
        o4.z = (acc[dt][rg * 4 + 2] + fb[wg * 3072 + (dt * 16 + rg * 4 + 2) * 64 + lane]) * inv;
        o4.w = (acc[dt][rg * 4 + 3] + fb[wg * 3072 + (dt * 16 + rg * 4 + 3) * 64 + lane]) * inv;
        *reinterpret_cast<float4*>(ob + dt * 32 + rg * 8 + h8 * 4) = o4;
      }
  }
}

extern "C" void kernel_launch(void* const* d_in, const int* in_sizes, int n_in,
                              void* d_out, int out_size, void* d_ws, size_t ws_size,
                              hipStream_t stream) {
  const float* x  = (const float*)d_in[0];
  const float* Wk = (const float*)d_in[1];
  const float* Wq = (const float*)d_in[2];
  const float* Wv = (const float*)d_in[3];
  unsigned short* ws = (unsigned short*)d_ws;
  unsigned short* Yk = ws + OYK;
  unsigned short* Yq = ws + OYQ;
  unsigned short* Vt = ws + OVT;

  convert_w<<<192, 256, 0, stream>>>(Wk, Wq, Wv, ws);
  proj_fused<<<256, 512, 0, stream>>>(x, ws, Yk, Yq, Vt);
  flash_attn<<<512, 512, 0, stream>>>(Yk, Yq, Vt, (float*)d_out);
}

// Round 3
// 164.002 us; speedup vs baseline: 2.5735x; 2.5735x over previous
//
#include <hip/hip_runtime.h>

// Fused causal attention head: B=4, T=4096, D=384, K=64.
// All operands FRAGMENT-LINEAR for 32x32x16 MFMA: frag = [lane(64)][j(8)] u16 (1KB),
// index: lane&31 = m/n, lane>>5 = k-half, j = k&7; ksegs of 16 k each.
// Yk/Yq: tile(b, t32) = 4 ksegs (feat 0..63)            -> 2048 u16
// Vt:    tile(b, d>>5, key>>7) = 8 ksegs (128 keys)     -> 4096 u16
// Wka/Wqa: tile(fout>>5) x 24 ksegs (fin)               -> 12288 u16 each x2
// Wvb:     tile(d>>5)    x 24 ksegs (fin)               -> 12288 u16 x12
// Softmax: fixed-base (no max) — scores/8 ~ O(1), exp2 args small, fp32-safe.

#define BB 4
#define TT 4096
#define DD 384

#define OWKA 0
#define OWQA 24576
#define OWVB 49152
#define OYK  196608
#define OYQ  1245184
#define OVT  2293760

#define C_EXP 0.18033688011112042f  // log2(e)/8

typedef __bf16 bf16x8 __attribute__((ext_vector_type(8)));
typedef float f32x16 __attribute__((ext_vector_type(16)));
typedef unsigned short u16x4 __attribute__((ext_vector_type(4)));

__device__ __forceinline__ unsigned short f2bf(float f) {
  unsigned int u = __builtin_bit_cast(unsigned int, f);
  u += 0x7FFFu + ((u >> 16) & 1u);
  return (unsigned short)(u >> 16);
}

__device__ __forceinline__ bf16x8 ldb8(const unsigned short* p) {
  return *reinterpret_cast<const bf16x8*>(p);
}

// ---------------- 1. Weight convert -> frag-linear (Wk/Wq A-frag, Wv B-frag) --------
__global__ __launch_bounds__(256) void convert_w(
    const float* __restrict__ Wk, const float* __restrict__ Wq,
    const float* __restrict__ Wv, unsigned short* __restrict__ ws) {
  int g = blockIdx.x * 256 + threadIdx.x;    // 512 rows x 96 float4 = 49152
  int row = g / 96;
  int fin = (g - row * 96) * 4;
  const float* src;
  unsigned short* dstbase;
  int m;
  if (row < 64)       { src = Wk + row * 384;         dstbase = ws + OWKA; m = row; }
  else if (row < 128) { src = Wq + (row - 64) * 384;  dstbase = ws + OWQA; m = row - 64; }
  else                { src = Wv + (row - 128) * 384; dstbase = ws + OWVB; m = row - 128; }
  float4 f = *reinterpret_cast<const float4*>(src + fin);
  u16x4 o;
  o[0] = f2bf(f.x); o[1] = f2bf(f.y); o[2] = f2bf(f.z); o[3] = f2bf(f.w);
  unsigned short* dst = dstbase + (m >> 5) * 12288 + (fin >> 4) * 512
                        + ((((fin >> 3) & 1) << 5) + (m & 31)) * 8 + (fin & 7);
  *reinterpret_cast<u16x4*>(dst) = o;
}

// ---------------- 2. Fused K/Q/V projection ----------------------------------------
// Block = 64 tokens, 512 threads (8 waves). X staged once in LDS frag-linear
// (serves as B-frag for K/Q and A-frag for V). Waves 0-1: Yk/Yq; waves 2-7: V.
__global__ __launch_bounds__(512) void proj_fused(
    const float* __restrict__ x, const unsigned short* __restrict__ ws_r,
    unsigned short* __restrict__ Yk, unsigned short* __restrict__ Yq,
    unsigned short* __restrict__ Vt) {
  __shared__ __align__(16) unsigned short xlds[24576];   // [t32(2)][kseg(24)][64][8]
  int tb = blockIdx.x;                        // 0..255
  int b = tb >> 6;
  int tid = threadIdx.x;
  // stage X: row r = tid>>3 (64 rows), e = tid&7 (segment of 48 feats)
  {
    int r = tid >> 3, e = tid & 7;
    const float* xr = x + (tb * 64 + r) * DD + e * 48;
#pragma unroll
    for (int i = 0; i < 12; i++) {
      int fin = e * 48 + i * 4;
      float4 f = *reinterpret_cast<const float4*>(xr + i * 4);
      u16x4 o;
      o[0] = f2bf(f.x); o[1] = f2bf(f.y); o[2] = f2bf(f.z); o[3] = f2bf(f.w);
      unsigned short* dst = xlds + (r >> 5) * 12288 + (fin >> 4) * 512
                            + ((((fin >> 3) & 1) << 5) + (r & 31)) * 8 + (fin & 7);
      *reinterpret_cast<u16x4*>(dst) = o;
    }
  }
  __syncthreads();
  int wid = tid >> 6, lane = tid & 63;
  int l31 = lane & 31, h8 = lane >> 5;
  const f32x16 fz16 = {};
  if (wid < 2) {
    // Yk (wid 0) / Yq (wid 1): A = W[2 mtiles], B = X[2 ntiles]
    const unsigned short* Wa = ws_r + (wid ? OWQA : OWKA) + lane * 8;
    unsigned short* Ysel = (wid ? Yq : Yk);
    f32x16 acc[2][2];
    acc[0][0] = fz16; acc[0][1] = fz16; acc[1][0] = fz16; acc[1][1] = fz16;
    for (int ks = 0; ks < 24; ks++) {
      bf16x8 a0 = ldb8(Wa + ks * 512);
      bf16x8 a1 = ldb8(Wa + 12288 + ks * 512);
      bf16x8 b0 = ldb8(xlds + ks * 512 + lane * 8);
      bf16x8 b1 = ldb8(xlds + 12288 + ks * 512 + lane * 8);
      acc[0][0] = __builtin_amdgcn_mfma_f32_32x32x16_bf16(a0, b0, acc[0][0], 0, 0, 0);
      acc[0][1] = __builtin_amdgcn_mfma_f32_32x32x16_bf16(a0, b1, acc[0][1], 0, 0, 0);
      acc[1][0] = __builtin_amdgcn_mfma_f32_32x32x16_bf16(a1, b0, acc[1][0], 0, 0, 0);
      acc[1][1] = __builtin_amdgcn_mfma_f32_32x32x16_bf16(a1, b1, acc[1][1], 0, 0, 0);
    }
    // C[fout = mt*32 + rg*8+4h8+i][token = tb*64 + nt*32 + l31]
#pragma unroll
    for (int mt = 0; mt < 2; mt++)
#pragma unroll
      for (int nt = 0; nt < 2; nt++) {
        int tile = b * 128 + (tb & 63) * 2 + nt;
#pragma unroll
        for (int rg = 0; rg < 4; rg++) {
          u16x4 o;
#pragma unroll
          for (int i = 0; i < 4; i++) o[i] = f2bf(acc[mt][nt][rg * 4 + i]);
          *reinterpret_cast<u16x4*>(Ysel + tile * 2048 + (mt * 2 + (rg >> 1)) * 512
                                    + (((rg & 1) << 5) + l31) * 8 + 4 * h8) = o;
        }
      }
  } else {
    // V: A = X[2 token tiles], B = Wv[2 d-tiles]; vw in [0,6)
    int vw = wid - 2;
    const unsigned short* Wb = ws_r + OWVB + vw * 2 * 12288 + lane * 8;
    f32x16 acc[2][2];
    acc[0][0] = fz16; acc[0][1] = fz16; acc[1][0] = fz16; acc[1][1] = fz16;
    for (int ks = 0; ks < 24; ks++) {
      bf16x8 a0 = ldb8(xlds + ks * 512 + lane * 8);
      bf16x8 a1 = ldb8(xlds + 12288 + ks * 512 + lane * 8);
      bf16x8 w0 = ldb8(Wb + ks * 512);
      bf16x8 w1 = ldb8(Wb + 12288 + ks * 512);
      acc[0][0] = __builtin_amdgcn_mfma_f32_32x32x16_bf16(a0, w0, acc[0][0], 0, 0, 0);
      acc[0][1] = __builtin_amdgcn_mfma_f32_32x32x16_bf16(a0, w1, acc[0][1], 0, 0, 0);
      acc[1][0] = __builtin_amdgcn_mfma_f32_32x32x16_bf16(a1, w0, acc[1][0], 0, 0, 0);
      acc[1][1] = __builtin_amdgcn_mfma_f32_32x32x16_bf16(a1, w1, acc[1][1], 0, 0, 0);
    }
    // C[key = tb*64 + t32*32 + rg*8+4h8+i][d = vw*64 + dt*32 + l31]
    int k128 = (tb & 63) >> 1;               // key-block WITHIN batch
#pragma unroll
    for (int t32 = 0; t32 < 2; t32++)
#pragma unroll
      for (int dt = 0; dt < 2; dt++) {
        int dti = vw * 2 + dt;
        unsigned short* vbase = Vt + ((b * 12 + dti) * 32 + k128) * 4096;
#pragma unroll
        for (int rg = 0; rg < 4; rg++) {
          u16x4 o;
#pragma unroll
          for (int i = 0; i < 4; i++) o[i] = f2bf(acc[t32][dt][rg * 4 + i]);
          int kseg = 4 * (tb & 1) + t32 * 2 + (rg >> 1);
          *reinterpret_cast<u16x4*>(vbase + kseg * 512
                                    + (((rg & 1) << 5) + l31) * 8 + 4 * h8) = o;
        }
      }
  }
}

// ---------------- 3. Flash attention: 8-wave blocks, in-block key split ------------
// b = (blk&7)>>1: each XCD works one batch -> Vt(b)+Yk(b) ~3.6MB fits its 4MB L2.
// Two 4-wave groups per block: group g handles key-blocks kb = 2*it + g.
// Wall iterations halve (1..16); constant 8 waves/CU (no idle-tail like round-0).
// Odd tail (kb == n128) masked free: its keys > qrow so causal test zeroes P; only
// addresses clamped. R1 lesson: cap 128 (512,4) spilled ~100 regs -> 925MB scratch
// traffic. Now (512,2) cap 256 — no spill — and PV operands streamed per-q to keep
// natural pressure low. LDS = 64KB, reused as fp32 staging for cross-group combine.
__global__ __launch_bounds__(512, 2) void flash_attn(
    const unsigned short* __restrict__ Yk, const unsigned short* __restrict__ Yq,
    const unsigned short* __restrict__ Vt, float* __restrict__ out) {
  __shared__ __align__(16) unsigned short pbuf[2][2][8192];  // [group][dbuf][kseg(8)][lane(64)][j(8)]
  int blk = blockIdx.x;
  int xcd = blk & 7;
  int b = xcd >> 1, half = xcd & 1;
  int n = blk >> 3;
  int st = (n < 32) ? (127 - 2 * n - half) : (2 * (n - 32) + half);
  int tid = threadIdx.x;
  int wid = tid >> 6, lane = tid & 63;
  int g = wid >> 2, wg = wid & 3;
  int l31 = lane & 31, h8 = lane >> 5;
  const f32x16 fz16 = {};
  const unsigned short* qbase = Yq + (b * 128 + st) * 2048 + lane * 8;
  bf16x8 qf[4];
#pragma unroll
  for (int ks = 0; ks < 4; ks++) qf[ks] = ldb8(qbase + ks * 512);
  f32x16 acc[3];
  acc[0] = fz16; acc[1] = fz16; acc[2] = fz16;
  float psum = 0.f;
  int n128 = (st >> 2) + 1;
  int W = (n128 + 1) >> 1;                   // wall iterations (uniform per block)
  int qrow = st * 32 + l31;
  const unsigned short* kbase = Yk + (b * 128 + wg) * 2048 + lane * 8;
  const unsigned short* vbase = Vt + ((b * 12 + wg * 3) * 32) * 4096 + lane * 8;
#pragma unroll 1
  for (int it = 0; it < W; it++) {
    int kb = 2 * it + g;
    int kbc = (kb < n128) ? kb : (n128 - 1);   // clamp addresses; P masked by causal test
    const unsigned short* kt = kbase + kbc * 8192;
    bf16x8 kf[4];
#pragma unroll
    for (int ks = 0; ks < 4; ks++) kf[ks] = ldb8(kt + ks * 512);
    f32x16 sacc = fz16;
#pragma unroll
    for (int ks = 0; ks < 4; ks++)
      sacc = __builtin_amdgcn_mfma_f32_32x32x16_bf16(kf[ks], qf[ks], sacc, 0, 0, 0);
    int kg0 = kb * 128 + wg * 32 + 4 * h8;     // real kb: masked iters have key > qrow
    unsigned short* pw = pbuf[g][it & 1];
#pragma unroll
    for (int rg = 0; rg < 4; rg++) {
      u16x4 o;
#pragma unroll
      for (int i = 0; i < 4; i++) {
        int key = kg0 + rg * 8 + i;
        float pv = (key > qrow) ? 0.f : exp2f(sacc[rg * 4 + i] * C_EXP);
        psum += pv;
        o[i] = f2bf(pv);
      }
      int gq = wg * 2 + (rg >> 1);
      *reinterpret_cast<u16x4*>(pw + gq * 512 + ((rg & 1) * 32 + l31) * 8 + 4 * h8) = o;
    }
    const unsigned short* vt = vbase + kbc * 4096;
    __syncthreads();
    // streamed PV: per q-group load 1 P frag + 3 V frags, then 3 MFMAs.
#pragma unroll
    for (int q = 0; q < 8; q++) {
      bf16x8 pfq = ldb8(pw + q * 512 + lane * 8);
      bf16x8 v0 = ldb8(vt + q * 512);
      bf16x8 v1 = ldb8(vt + 32 * 4096 + q * 512);
      bf16x8 v2 = ldb8(vt + 64 * 4096 + q * 512);
      acc[0] = __builtin_amdgcn_mfma_f32_32x32x16_bf16(v0, pfq, acc[0], 0, 0, 0);
      acc[1] = __builtin_amdgcn_mfma_f32_32x32x16_bf16(v1, pfq, acc[1], 0, 0, 0);
      acc[2] = __builtin_amdgcn_mfma_f32_32x32x16_bf16(v2, pfq, acc[2], 0, 0, 0);
    }
  }
  // ---- cross-group combine: reuse pbuf as fp32 staging ----
  // words [0, 12288): group1 acc (wave wg: wg*3072 + (dt*16+e)*64 + lane)
  // words [12288, 12544): per-wave psum (wid*32 + l31)
  psum += __shfl_xor(psum, 32);
  __syncthreads();                           // all P reads done; safe to overwrite
  float* fb = reinterpret_cast<float*>(pbuf);
  if (h8 == 0) fb[12288 + wid * 32 + l31] = psum;
  if (g == 1) {
#pragma unroll
    for (int dt = 0; dt < 3; dt++)
#pragma unroll
      for (int e = 0; e < 16; e++)
        fb[wg * 3072 + (dt * 16 + e) * 64 + lane] = acc[dt][e];
  }
  __syncthreads();
  if (g == 0) {
    float lt = 0.f;
#pragma unroll
    for (int w = 0; w < 8; w++) lt += fb[12288 + w * 32 + l31];
    float inv = 1.0f / lt;
    float* ob = out + (b * TT + st * 32 + l31) * DD + wg * 96;
#pragma unroll
    for (int dt = 0; dt < 3; dt++)
#pragma unroll
      for (int rg = 0; rg < 4; rg++) {
        float4 o4;
        o4.x = (acc[dt][rg * 4 + 0] + fb[wg * 3072 + (dt * 16 + rg * 4 + 0) * 64 + lane]) * inv;
        o4.y = (acc[dt][rg * 4 + 1] + fb[wg * 3072 + (dt * 16 + rg * 4 + 1) * 64 + lane]) * inv;
        o4.z = (acc[dt][rg * 4 + 2] + fb[wg * 3072 + (dt * 16 + rg * 4 + 2) * 64 + lane]) * inv;
        o4.w = (acc[dt][rg * 4 + 3] + fb[wg * 3072 + (dt * 16 + rg * 4 + 3) * 64 + lane]) * inv;
        *reinterpret_cast<float4*>(ob + dt * 32 + rg * 8 + h8 * 4) = o4;
      }
  }
}

extern "C" void kernel_launch(void* const* d_in, const int* in_sizes, int n_in,
                              void* d_out, int out_size, void* d_ws, size_t ws_size,
                              hipStream_t stream) {
  const float* x  = (const float*)d_in[0];
  const float* Wk = (const float*)d_in[1];
  const float* Wq = (const float*)d_in[2];
  const float* Wv = (const float*)d_in[3];
  unsigned short* ws = (unsigned short*)d_ws;
  unsigned short* Yk = ws + OYK;
  unsigned short* Yq = ws + OYQ;
  unsigned short* Vt = ws + OVT;

  convert_w<<<192, 256, 0, stream>>>(Wk, Wq, Wv, ws);
  proj_fused<<<256, 512, 0, stream>>>(x, ws, Yk, Yq, Vt);
  flash_attn<<<512, 512, 0, stream>>>(Yk, Yq, Vt, (float*)d_out);
}

// Round 6
// 160.208 us; speedup vs baseline: 2.6345x; 1.0237x over previous
//
#include <hip/hip_runtime.h>

// Fused causal attention head: B=4, T=4096, D=384, K=64.
// All operands FRAGMENT-LINEAR for 32x32x16 MFMA: frag = [lane(64)][j(8)] u16 (1KB),
// index: lane&31 = m/n, lane>>5 = k-half, j = k&7; ksegs of 16 k each.
// Yk/Yq: tile(b, t32) = 4 ksegs (feat 0..63)            -> 2048 u16
// Vt:    tile(b, d>>5, key>>7) = 8 ksegs (128 keys)     -> 4096 u16
// Wka/Wqa: tile(fout>>5) x 24 ksegs (fin)               -> 12288 u16 each x2
// Wvb:     tile(d>>5)    x 24 ksegs (fin)               -> 12288 u16 x12
// Softmax: fixed-base (no max) — scores/8 ~ O(1), exp2 args small, fp32-safe.

#define BB 4
#define TT 4096
#define DD 384

#define OWKA 0
#define OWQA 24576
#define OWVB 49152
#define OYK  196608
#define OYQ  1245184
#define OVT  2293760

#define C_EXP 0.18033688011112042f  // log2(e)/8

typedef __bf16 bf16x8 __attribute__((ext_vector_type(8)));
typedef float f32x16 __attribute__((ext_vector_type(16)));
typedef unsigned short u16x4 __attribute__((ext_vector_type(4)));

__device__ __forceinline__ unsigned short f2bf(float f) {
  unsigned int u = __builtin_bit_cast(unsigned int, f);
  u += 0x7FFFu + ((u >> 16) & 1u);
  return (unsigned short)(u >> 16);
}

__device__ __forceinline__ bf16x8 ldb8(const unsigned short* p) {
  return *reinterpret_cast<const bf16x8*>(p);
}

// ---------------- 1. Weight convert -> frag-linear (Wk/Wq A-frag, Wv B-frag) --------
__global__ __launch_bounds__(256) void convert_w(
    const float* __restrict__ Wk, const float* __restrict__ Wq,
    const float* __restrict__ Wv, unsigned short* __restrict__ ws) {
  int g = blockIdx.x * 256 + threadIdx.x;    // 512 rows x 96 float4 = 49152
  int row = g / 96;
  int fin = (g - row * 96) * 4;
  const float* src;
  unsigned short* dstbase;
  int m;
  if (row < 64)       { src = Wk + row * 384;         dstbase = ws + OWKA; m = row; }
  else if (row < 128) { src = Wq + (row - 64) * 384;  dstbase = ws + OWQA; m = row - 64; }
  else                { src = Wv + (row - 128) * 384; dstbase = ws + OWVB; m = row - 128; }
  float4 f = *reinterpret_cast<const float4*>(src + fin);
  u16x4 o;
  o[0] = f2bf(f.x); o[1] = f2bf(f.y); o[2] = f2bf(f.z); o[3] = f2bf(f.w);
  unsigned short* dst = dstbase + (m >> 5) * 12288 + (fin >> 4) * 512
                        + ((((fin >> 3) & 1) << 5) + (m & 31)) * 8 + (fin & 7);
  *reinterpret_cast<u16x4*>(dst) = o;
}

// ---------------- 2. Fused K/Q/V projection ----------------------------------------
// Block = 64 tokens, 512 threads (8 waves). X staged once in LDS frag-linear
// (serves as B-frag for K/Q and A-frag for V). Waves 0-1: Yk/Yq; waves 2-7: V.
__global__ __launch_bounds__(512) void proj_fused(
    const float* __restrict__ x, const unsigned short* __restrict__ ws_r,
    unsigned short* __restrict__ Yk, unsigned short* __restrict__ Yq,
    unsigned short* __restrict__ Vt) {
  __shared__ __align__(16) unsigned short xlds[24576];   // [t32(2)][kseg(24)][64][8]
  int tb = blockIdx.x;                        // 0..255
  int b = tb >> 6;
  int tid = threadIdx.x;
  // stage X: row r = tid>>3 (64 rows), e = tid&7 (segment of 48 feats)
  {
    int r = tid >> 3, e = tid & 7;
    const float* xr = x + (tb * 64 + r) * DD + e * 48;
#pragma unroll
    for (int i = 0; i < 12; i++) {
      int fin = e * 48 + i * 4;
      float4 f = *reinterpret_cast<const float4*>(xr + i * 4);
      u16x4 o;
      o[0] = f2bf(f.x); o[1] = f2bf(f.y); o[2] = f2bf(f.z); o[3] = f2bf(f.w);
      unsigned short* dst = xlds + (r >> 5) * 12288 + (fin >> 4) * 512
                            + ((((fin >> 3) & 1) << 5) + (r & 31)) * 8 + (fin & 7);
      *reinterpret_cast<u16x4*>(dst) = o;
    }
  }
  __syncthreads();
  int wid = tid >> 6, lane = tid & 63;
  int l31 = lane & 31, h8 = lane >> 5;
  const f32x16 fz16 = {};
  if (wid < 2) {
    // Yk (wid 0) / Yq (wid 1): A = W[2 mtiles], B = X[2 ntiles]
    const unsigned short* Wa = ws_r + (wid ? OWQA : OWKA) + lane * 8;
    unsigned short* Ysel = (wid ? Yq : Yk);
    f32x16 acc[2][2];
    acc[0][0] = fz16; acc[0][1] = fz16; acc[1][0] = fz16; acc[1][1] = fz16;
    for (int ks = 0; ks < 24; ks++) {
      bf16x8 a0 = ldb8(Wa + ks * 512);
      bf16x8 a1 = ldb8(Wa + 12288 + ks * 512);
      bf16x8 b0 = ldb8(xlds + ks * 512 + lane * 8);
      bf16x8 b1 = ldb8(xlds + 12288 + ks * 512 + lane * 8);
      acc[0][0] = __builtin_amdgcn_mfma_f32_32x32x16_bf16(a0, b0, acc[0][0], 0, 0, 0);
      acc[0][1] = __builtin_amdgcn_mfma_f32_32x32x16_bf16(a0, b1, acc[0][1], 0, 0, 0);
      acc[1][0] = __builtin_amdgcn_mfma_f32_32x32x16_bf16(a1, b0, acc[1][0], 0, 0, 0);
      acc[1][1] = __builtin_amdgcn_mfma_f32_32x32x16_bf16(a1, b1, acc[1][1], 0, 0, 0);
    }
    // C[fout = mt*32 + rg*8+4h8+i][token = tb*64 + nt*32 + l31]
#pragma unroll
    for (int mt = 0; mt < 2; mt++)
#pragma unroll
      for (int nt = 0; nt < 2; nt++) {
        int tile = b * 128 + (tb & 63) * 2 + nt;
#pragma unroll
        for (int rg = 0; rg < 4; rg++) {
          u16x4 o;
#pragma unroll
          for (int i = 0; i < 4; i++) o[i] = f2bf(acc[mt][nt][rg * 4 + i]);
          *reinterpret_cast<u16x4*>(Ysel + tile * 2048 + (mt * 2 + (rg >> 1)) * 512
                                    + (((rg & 1) << 5) + l31) * 8 + 4 * h8) = o;
        }
      }
  } else {
    // V: A = X[2 token tiles], B = Wv[2 d-tiles]; vw in [0,6)
    int vw = wid - 2;
    const unsigned short* Wb = ws_r + OWVB + vw * 2 * 12288 + lane * 8;
    f32x16 acc[2][2];
    acc[0][0] = fz16; acc[0][1] = fz16; acc[1][0] = fz16; acc[1][1] = fz16;
    for (int ks = 0; ks < 24; ks++) {
      bf16x8 a0 = ldb8(xlds + ks * 512 + lane * 8);
      bf16x8 a1 = ldb8(xlds + 12288 + ks * 512 + lane * 8);
      bf16x8 w0 = ldb8(Wb + ks * 512);
      bf16x8 w1 = ldb8(Wb + 12288 + ks * 512);
      acc[0][0] = __builtin_amdgcn_mfma_f32_32x32x16_bf16(a0, w0, acc[0][0], 0, 0, 0);
      acc[0][1] = __builtin_amdgcn_mfma_f32_32x32x16_bf16(a0, w1, acc[0][1], 0, 0, 0);
      acc[1][0] = __builtin_amdgcn_mfma_f32_32x32x16_bf16(a1, w0, acc[1][0], 0, 0, 0);
      acc[1][1] = __builtin_amdgcn_mfma_f32_32x32x16_bf16(a1, w1, acc[1][1], 0, 0, 0);
    }
    // C[key = tb*64 + t32*32 + rg*8+4h8+i][d = vw*64 + dt*32 + l31]
    int k128 = (tb & 63) >> 1;               // key-block WITHIN batch
#pragma unroll
    for (int t32 = 0; t32 < 2; t32++)
#pragma unroll
      for (int dt = 0; dt < 2; dt++) {
        int dti = vw * 2 + dt;
        unsigned short* vbase = Vt + ((b * 12 + dti) * 32 + k128) * 4096;
#pragma unroll
        for (int rg = 0; rg < 4; rg++) {
          u16x4 o;
#pragma unroll
          for (int i = 0; i < 4; i++) o[i] = f2bf(acc[t32][dt][rg * 4 + i]);
          int kseg = 4 * (tb & 1) + t32 * 2 + (rg >> 1);
          *reinterpret_cast<u16x4*>(vbase + kseg * 512
                                    + (((rg & 1) << 5) + l31) * 8 + 4 * h8) = o;
        }
      }
  }
}

// ---------------- 3. Flash attention: 8-wave blocks, in-block key split ------------
// b = (blk&7)>>1: each XCD works one batch -> Vt(b)+Yk(b) ~3.6MB fits its 4MB L2.
// Two 4-wave groups per block: group g handles key-blocks kb = 2*it + g.
// Wall iterations halve (1..16); W_max = 16 (vs 32 single-group) sets the wall.
// Odd tail (kb == n128) masked free: its keys > qrow so causal test zeroes P.
// R1 lesson: (512,4) cap spilled ~100 regs -> 925MB scratch. R3 lesson: "streamed"
// PV loads let compiler allocate only 64 VGPR -> ~4 loads in flight -> latency-
// serialized iters (19 B/cyc/CU), 78us. R4: round-0's BULK pre-barrier V loads
// restored (24 frags in flight issued under QK/exp/barrier latency) under the
// (512,2) 256-reg cap. LDS = 64KB, reused as fp32 staging for cross-group combine.
__global__ __launch_bounds__(512, 2) void flash_attn(
    const unsigned short* __restrict__ Yk, const unsigned short* __restrict__ Yq,
    const unsigned short* __restrict__ Vt, float* __restrict__ out) {
  __shared__ __align__(16) unsigned short pbuf[2][2][8192];  // [group][dbuf][kseg(8)][lane(64)][j(8)]
  int blk = blockIdx.x;
  int xcd = blk & 7;
  int b = xcd >> 1, half = xcd & 1;
  int n = blk >> 3;
  int st = (n < 32) ? (127 - 2 * n - half) : (2 * (n - 32) + half);
  int tid = threadIdx.x;
  int wid = tid >> 6, lane = tid & 63;
  int g = wid >> 2, wg = wid & 3;
  int l31 = lane & 31, h8 = lane >> 5;
  const f32x16 fz16 = {};
  const unsigned short* qbase = Yq + (b * 128 + st) * 2048 + lane * 8;
  bf16x8 qf[4];
#pragma unroll
  for (int ks = 0; ks < 4; ks++) qf[ks] = ldb8(qbase + ks * 512);
  f32x16 acc[3];
  acc[0] = fz16; acc[1] = fz16; acc[2] = fz16;
  float psum = 0.f;
  int n128 = (st >> 2) + 1;
  int W = (n128 + 1) >> 1;                   // wall iterations (uniform per block)
  int qrow = st * 32 + l31;
  const unsigned short* kbase = Yk + (b * 128 + wg) * 2048 + lane * 8;
  const unsigned short* vbase = Vt + ((b * 12 + wg * 3) * 32) * 4096 + lane * 8;
#pragma unroll 1
  for (int it = 0; it < W; it++) {
    int kb = 2 * it + g;
    int kbc = (kb < n128) ? kb : (n128 - 1);   // clamp addresses; P masked by causal test
    const unsigned short* kt = kbase + kbc * 8192;
    bf16x8 kf[4];
#pragma unroll
    for (int ks = 0; ks < 4; ks++) kf[ks] = ldb8(kt + ks * 512);
    f32x16 sacc = fz16;
#pragma unroll
    for (int ks = 0; ks < 4; ks++)
      sacc = __builtin_amdgcn_mfma_f32_32x32x16_bf16(kf[ks], qf[ks], sacc, 0, 0, 0);
    int kg0 = kb * 128 + wg * 32 + 4 * h8;     // real kb: masked iters have key > qrow
    unsigned short* pw = pbuf[g][it & 1];
#pragma unroll
    for (int rg = 0; rg < 4; rg++) {
      u16x4 o;
#pragma unroll
      for (int i = 0; i < 4; i++) {
        int key = kg0 + rg * 8 + i;
        float pv = (key > qrow) ? 0.f : exp2f(sacc[rg * 4 + i] * C_EXP);
        psum += pv;
        o[i] = f2bf(pv);
      }
      int gq = wg * 2 + (rg >> 1);
      *reinterpret_cast<u16x4*>(pw + gq * 512 + ((rg & 1) * 32 + l31) * 8 + 4 * h8) = o;
    }
    // BULK pre-barrier V loads: 24 frags in flight while QK/exp/barrier latency elapses
    const unsigned short* vt = vbase + kbc * 4096;
    bf16x8 vf0[8], vf1[8], vf2[8];
#pragma unroll
    for (int q = 0; q < 8; q++) vf0[q] = ldb8(vt + q * 512);
#pragma unroll
    for (int q = 0; q < 8; q++) vf1[q] = ldb8(vt + 32 * 4096 + q * 512);
#pragma unroll
    for (int q = 0; q < 8; q++) vf2[q] = ldb8(vt + 64 * 4096 + q * 512);
    __syncthreads();
    bf16x8 pf[8];
#pragma unroll
    for (int q = 0; q < 8; q++) pf[q] = ldb8(pw + q * 512 + lane * 8);
#pragma unroll
    for (int q = 0; q < 8; q++) {
      acc[0] = __builtin_amdgcn_mfma_f32_32x32x16_bf16(vf0[q], pf[q], acc[0], 0, 0, 0);
      acc[1] = __builtin_amdgcn_mfma_f32_32x32x16_bf16(vf1[q], pf[q], acc[1], 0, 0, 0);
      acc[2] = __builtin_amdgcn_mfma_f32_32x32x16_bf16(vf2[q], pf[q], acc[2], 0, 0, 0);
    }
  }
  // ---- cross-group combine: reuse pbuf as fp32 staging ----
  // words [0, 12288): group1 acc (wave wg: wg*3072 + (dt*16+e)*64 + lane)
  // words [12288, 12544): per-wave psum (wid*32 + l31)
  psum += __shfl_xor(psum, 32);
  __syncthreads();                           // all P reads done; safe to overwrite
  float* fb = reinterpret_cast<float*>(pbuf);
  if (h8 == 0) fb[12288 + wid * 32 + l31] = psum;
  if (g == 1) {
#pragma unroll
    for (int dt = 0; dt < 3; dt++)
#pragma unroll
      for (int e = 0; e < 16; e++)
        fb[wg * 3072 + (dt * 16 + e) * 64 + lane] = acc[dt][e];
  }
  __syncthreads();
  if (g == 0) {
    float lt = 0.f;
#pragma unroll
    for (int w = 0; w < 8; w++) lt += fb[12288 + w * 32 + l31];
    float inv = 1.0f / lt;
    float* ob = out + (b * TT + st * 32 + l31) * DD + wg * 96;
#pragma unroll
    for (int dt = 0; dt < 3; dt++)
#pragma unroll
      for (int rg = 0; rg < 4; rg++) {
        float4 o4;
        o4.x = (acc[dt][rg * 4 + 0] + fb[wg * 3072 + (dt * 16 + rg * 4 + 0) * 64 + lane]) * inv;
        o4.y = (acc[dt][rg * 4 + 1] + fb[wg * 3072 + (dt * 16 + rg * 4 + 1) * 64 + lane]) * inv;
        o4.z = (acc[dt][rg * 4 + 2] + fb[wg * 3072 + (dt * 16 + rg * 4 + 2) * 64 + lane]) * inv;
        o4.w = (acc[dt][rg * 4 + 3] + fb[wg * 3072 + (dt * 16 + rg * 4 + 3) * 64 + lane]) * inv;
        *reinterpret_cast<float4*>(ob + dt * 32 + rg * 8 + h8 * 4) = o4;
      }
  }
}

extern "C" void kernel_launch(void* const* d_in, const int* in_sizes, int n_in,
                              void* d_out, int out_size, void* d_ws, size_t ws_size,
                              hipStream_t stream) {
  const float* x  = (const float*)d_in[0];
  const float* Wk = (const float*)d_in[1];
  const float* Wq = (const float*)d_in[2];
  const float* Wv = (const float*)d_in[3];
  unsigned short* ws = (unsigned short*)d_ws;
  unsigned short* Yk = ws + OYK;
  unsigned short* Yq = ws + OYQ;
  unsigned short* Vt = ws + OVT;

  convert_w<<<192, 256, 0, stream>>>(Wk, Wq, Wv, ws);
  proj_fused<<<256, 512, 0, stream>>>(x, ws, Yk, Yq, Vt);
  flash_attn<<<512, 512, 0, stream>>>(Yk, Yq, Vt, (float*)d_out);
}